// Round 11
// baseline (248.099 us; speedup 1.0000x reference)
//
#include <hip/hip_runtime.h>
#include <hip/hip_bf16.h>
#include <stdint.h>

// MHA: B=1, L=4096, D=1024, H=16, dk=64.
// Inputs fp32, OUTPUT fp32. Internal compute bf16 with fp32 accumulation.
//
// v13 (resubmit — R10 was an infra failure, container never ran the bench):
//  - gemm_qkv: 128x128 tile (m97-ladder shape, 874-TF class) + the v12
//    dbuf/stage-ahead/single-barrier schedule + the R6-verified 128^2
//    LDS-routed frag-major epilogue.  The 64-tile (v11/v12) ran at ~260-340
//    TF-class; the 128^2 retile halves staged bytes per MFMA.  Grid 768 ->
//    3 blocks/CU with dbuf hiding the staging latency in-block.
//  - gemm_out: EXACT v12 (64x128 dbuf).  flash: EXACT v9 (77.7us best).
//    cast: unchanged.  One change this round for clean attribution.

typedef __bf16 bf16_t;
typedef __bf16 bf16x8 __attribute__((ext_vector_type(8)));
typedef __bf16 bf16x4 __attribute__((ext_vector_type(4)));
typedef float f32x4 __attribute__((ext_vector_type(4)));
typedef unsigned short u16x8 __attribute__((ext_vector_type(8)));

#define MFMA_BF16 __builtin_amdgcn_mfma_f32_16x16x32_bf16

__device__ __forceinline__ void async_copy16(const void* g, void* lds) {
  __builtin_amdgcn_global_load_lds(
      (__attribute__((address_space(1))) void*)(uintptr_t)g,
      (__attribute__((address_space(3))) void*)lds, 16, 0, 0);
}

// ---------------------------------------------------------------------------
// fp32 -> bf16 cast, 8 elems/thread, z selects tensor.
// ---------------------------------------------------------------------------
__global__ __launch_bounds__(256) void cast_f32_bf16(
    const float* __restrict__ s0, bf16_t* __restrict__ d0, int n0,
    const float* __restrict__ s1, bf16_t* __restrict__ d1, int n1,
    const float* __restrict__ s2, bf16_t* __restrict__ d2, int n2,
    const float* __restrict__ s3, bf16_t* __restrict__ d3, int n3,
    const float* __restrict__ s4, bf16_t* __restrict__ d4, int n4,
    const float* __restrict__ s5, bf16_t* __restrict__ d5, int n5,
    const float* __restrict__ s6, bf16_t* __restrict__ d6, int n6) {
  const float* s;
  bf16_t* d;
  int n;
  switch (blockIdx.z) {
    case 0: s = s0; d = d0; n = n0; break;
    case 1: s = s1; d = d1; n = n1; break;
    case 2: s = s2; d = d2; n = n2; break;
    case 3: s = s3; d = d3; n = n3; break;
    case 4: s = s4; d = d4; n = n4; break;
    case 5: s = s5; d = d5; n = n5; break;
    default: s = s6; d = d6; n = n6; break;
  }
  const int i = (blockIdx.x * 256 + threadIdx.x) * 8;
  if (i >= n) return;
  float4 a = *(const float4*)(s + i);
  float4 b = *(const float4*)(s + i + 4);
  bf16x8 o;
  o[0] = (bf16_t)a.x; o[1] = (bf16_t)a.y; o[2] = (bf16_t)a.z; o[3] = (bf16_t)a.w;
  o[4] = (bf16_t)b.x; o[5] = (bf16_t)b.y; o[6] = (bf16_t)b.z; o[7] = (bf16_t)b.w;
  *(bf16x8*)(d + i) = o;
}

// ---------------------------------------------------------------------------
// QKV projection GEMM, tile 128x128, BK=32, 4 waves 2x2 (m97 shape), LDS
// double-buffer with stage-ahead + single barrier per iter.
// z=0 -> Qt (scaled), z=1 -> Kt, z=2 -> Vt (transposed+P-packet-permuted).
// Epilogue (R6-verified): acc -> 32KB LDS image in frag-granule order
// (reuses the dbuf pool after a barrier) -> 8 linear passes of dwordx4 into
// the TWO contiguous 16KB regions the 128x128 C-tile occupies.
// ---------------------------------------------------------------------------
__global__ __launch_bounds__(256) void gemm_qkv(
    const bf16_t* __restrict__ A0, const bf16_t* __restrict__ W0,
    const float* __restrict__ b0, bf16_t* __restrict__ D0,
    const bf16_t* __restrict__ A1, const bf16_t* __restrict__ W1,
    const float* __restrict__ b1, bf16_t* __restrict__ D1,
    const bf16_t* __restrict__ A2, const bf16_t* __restrict__ W2,
    const float* __restrict__ b2, bf16_t* __restrict__ D2,
    int M, int N, int K) {
  const bf16_t *A, *W;
  const float* bias;
  bf16_t* D;
  const int zz = blockIdx.z;
  if (zz == 0)      { A = A0; W = W0; bias = b0; D = D0; }
  else if (zz == 1) { A = A1; W = W1; bias = b1; D = D1; }
  else              { A = A2; W = W2; bias = b2; D = D2; }

  // buffer b at smem + b*16384: A 128x32 (8KB) then B 128x32 (8KB).
  __shared__ __align__(16) char smem[32768];

  const int t = threadIdx.x;
  const int w = t >> 6, lane = t & 63;
  const int quad = lane >> 4, l16 = lane & 15;
  const int wr = w >> 1, wc = w & 1;
  const int m0 = blockIdx.x * 128;
  const int n0 = blockIdx.y * 128;
  const int srow = lane >> 2;
  const int scol = (lane & 3) * 8;

  f32x4 acc[4][4] = {};

#define GSTAGE(k0_, b_)                                                       \
  {                                                                           \
    char* base_ = (char*)smem + (b_) * 16384;                                 \
    async_copy16(&A[(size_t)(m0 + (2 * w) * 16 + srow) * K + (k0_) + scol],   \
                 base_ + (2 * w) * 1024);                                     \
    async_copy16(                                                             \
        &A[(size_t)(m0 + (2 * w + 1) * 16 + srow) * K + (k0_) + scol],        \
        base_ + (2 * w + 1) * 1024);                                          \
    async_copy16(&W[(size_t)(n0 + (2 * w) * 16 + srow) * K + (k0_) + scol],   \
                 base_ + 8192 + (2 * w) * 1024);                              \
    async_copy16(                                                             \
        &W[(size_t)(n0 + (2 * w + 1) * 16 + srow) * K + (k0_) + scol],        \
        base_ + 8192 + (2 * w + 1) * 1024);                                   \
  }

  GSTAGE(0, 0);

  const int NIT = K / 32;  // 32
  for (int i = 0; i < NIT; i++) {
    const int b = i & 1;
    asm volatile("s_waitcnt vmcnt(0)" ::: "memory");  // STAGE(i): full iter old
    __builtin_amdgcn_s_barrier();
    __builtin_amdgcn_sched_barrier(0);
    if (i + 1 < NIT) GSTAGE((i + 1) * 32, b ^ 1);

    const bf16_t(*As)[32] =
        reinterpret_cast<const bf16_t(*)[32]>(smem + b * 16384);
    const bf16_t(*Bs)[32] =
        reinterpret_cast<const bf16_t(*)[32]>(smem + b * 16384 + 8192);

    bf16x8 af[4], bfr[4];
#pragma unroll
    for (int mt = 0; mt < 4; mt++)
      af[mt] = *(const bf16x8*)&As[wr * 64 + mt * 16 + l16][quad * 8];
#pragma unroll
    for (int nt = 0; nt < 4; nt++)
      bfr[nt] = *(const bf16x8*)&Bs[wc * 64 + nt * 16 + l16][quad * 8];
#pragma unroll
    for (int mt = 0; mt < 4; mt++)
#pragma unroll
      for (int nt = 0; nt < 4; nt++)
        acc[mt][nt] = MFMA_BF16(af[mt], bfr[nt], acc[mt][nt], 0, 0, 0);
  }
#undef GSTAGE
  __syncthreads();  // all waves done reading both buffers before Ep overwrite

  // ---- epilogue: dump acc into 32KB LDS image (frag-granule order) ----
  bf16_t* Ep = (bf16_t*)smem;  // [wc][granule 0..7][1024]
  if (zz < 2) {
    const float qs = (zz == 0) ? 0.125f * 1.44269504088896340736f : 1.0f;
#pragma unroll
    for (int nt = 0; nt < 4; nt++) {
      const int col = n0 + wc * 64 + nt * 16 + l16;
      const float bb = bias[col];
      // dk = nt*16 + l16
      const int igb = ((nt >> 1) * 64 + ((2 * nt + (l16 >> 3)) & 3) * 16) * 8 +
                      (l16 & 7);
#pragma unroll
      for (int mt = 0; mt < 4; mt++) {
        const int gr = wc * 8 + wr * 4 + mt;  // LDS granule
#pragma unroll
        for (int r = 0; r < 4; r++) {
          Ep[gr * 1024 + igb + (quad * 4 + r) * 8] =
              (bf16_t)((acc[mt][nt][r] + bb) * qs);
        }
      }
    }
  } else {
#pragma unroll
    for (int nt = 0; nt < 4; nt++) {
      const int col = n0 + wc * 64 + nt * 16 + l16;
      const float bb = bias[col];
#pragma unroll
      for (int mt = 0; mt < 4; mt++) {
        const int gr = wc * 8 + wr * 4 + nt;  // V granule: (kvchunk=wr, dkt=nt)
        const int ig = ((mt >> 1) * 64 + quad * 16 + l16) * 8 + ((mt & 1) << 2);
        bf16x4 pk;
#pragma unroll
        for (int r = 0; r < 4; r++) pk[r] = (bf16_t)(acc[mt][nt][r] + bb);
        *(bf16x4*)&Ep[gr * 1024 + ig] = pk;
      }
    }
  }
  __syncthreads();

  // ---- linear copy: 2 contiguous 16KB regions, 16B/lane coalesced ----
  const int hh0 = n0 >> 6;
  const size_t gb = (zz < 2) ? (size_t)(m0 >> 4) : (size_t)(m0 >> 6) * 4;
#pragma unroll
  for (int p = 0; p < 8; p++) {
    const int f = (p * 256 + t) * 8;       // elem index in Ep
    const int wcr = f >> 13;               // region (head-half)
    const int off = f & 8191;              // elem within region
    const float4 vv = *(const float4*)&Ep[f];
    *(float4*)(D + ((size_t)(hh0 + wcr) * 256 + gb) * 1024 + off) = vv;
  }
}

// ---------------------------------------------------------------------------
// Output GEMM: C = A @ W^T + b (fp32 out).  Tile 64x128, dbuf stage-ahead.
// (EXACT v12.)
// ---------------------------------------------------------------------------
__global__ __launch_bounds__(256) void gemm_out(
    const bf16_t* __restrict__ A, const bf16_t* __restrict__ W,
    const float* __restrict__ bias, float* __restrict__ C, int M, int N,
    int K) {
  __shared__ __align__(16) char smem[24576];

  const int t = threadIdx.x;
  const int w = t >> 6, lane = t & 63;
  const int quad = lane >> 4, l16 = lane & 15;
  const int wr = w >> 1, wc = w & 1;
  const int m0 = blockIdx.x * 64;
  const int n0 = blockIdx.y * 128;
  const int srow = t >> 2;
  const int scol = (t & 3) * 8;

  f32x4 acc[2][4] = {};

#define GSTAGE(k0_, b_)                                                     \
  {                                                                         \
    async_copy16(&A[(size_t)(m0 + srow) * K + (k0_) + scol],                \
                 (char*)smem + (b_) * 12288 + t * 16);                      \
    async_copy16(&W[(size_t)(n0 + srow) * K + (k0_) + scol],                \
                 (char*)smem + (b_) * 12288 + 4096 + t * 16);               \
    async_copy16(&W[(size_t)(n0 + 64 + srow) * K + (k0_) + scol],           \
                 (char*)smem + (b_) * 12288 + 8192 + t * 16);               \
  }

  GSTAGE(0, 0);

  const int NIT = K / 32;
  for (int i = 0; i < NIT; i++) {
    const int b = i & 1;
    asm volatile("s_waitcnt vmcnt(0)" ::: "memory");
    __builtin_amdgcn_s_barrier();
    __builtin_amdgcn_sched_barrier(0);
    if (i + 1 < NIT) GSTAGE((i + 1) * 32, b ^ 1);

    const bf16_t(*As)[32] =
        reinterpret_cast<const bf16_t(*)[32]>(smem + b * 12288);
    const bf16_t(*Bs)[32] =
        reinterpret_cast<const bf16_t(*)[32]>(smem + b * 12288 + 4096);

    bf16x8 af[2], bfr[4];
#pragma unroll
    for (int mt = 0; mt < 2; mt++)
      af[mt] = *(const bf16x8*)&As[wr * 32 + mt * 16 + l16][quad * 8];
#pragma unroll
    for (int nt = 0; nt < 4; nt++)
      bfr[nt] = *(const bf16x8*)&Bs[wc * 64 + nt * 16 + l16][quad * 8];
#pragma unroll
    for (int mt = 0; mt < 2; mt++)
#pragma unroll
      for (int nt = 0; nt < 4; nt++)
        acc[mt][nt] = MFMA_BF16(af[mt], bfr[nt], acc[mt][nt], 0, 0, 0);
  }
#undef GSTAGE

#pragma unroll
  for (int nt = 0; nt < 4; nt++) {
    const int col = n0 + wc * 64 + nt * 16 + l16;
    const float bb = bias[col];
#pragma unroll
    for (int mt = 0; mt < 2; mt++) {
#pragma unroll
      for (int r = 0; r < 4; r++) {
        const int row = m0 + wr * 32 + mt * 16 + quad * 4 + r;
        C[(size_t)row * N + col] = acc[mt][nt][r] + bb;
      }
    }
  }
}

// ---------------------------------------------------------------------------
// Flash v9 (EXACT — best measured 77.7us).  8 waves, kv-parity split, Nq=2,
// in-register P, two-phase counted-vmcnt schedule:
//   phase A: s_waitcnt vmcnt(2) [own K(i) landed] ; s_barrier ;
//            STAGE(i+1) ; read K ; QK MFMAs (setprio) ; softmax -> pb regs
//   phase B: s_waitcnt vmcnt(4) [own V(i) landed] ; s_barrier ;
//            read V ; PV MFMAs (setprio)
// Prefetch for iter i+1 stays IN FLIGHT across both barriers; last iter
// peeled for the final drain.
// ---------------------------------------------------------------------------
__global__ __launch_bounds__(512, 4) void flash_attn(
    const bf16_t* __restrict__ Qt, const bf16_t* __restrict__ Kt,
    const bf16_t* __restrict__ Vt, bf16_t* __restrict__ O, int L) {
  // linear block id lands on XCD i%8 (round-robin dispatch): 2 heads/XCD.
  const int i = blockIdx.x;
  const int slot = i >> 3;                  // 0..63 within XCD
  const int h = (i & 7) * 2 + (slot >> 5);  // 2 heads per XCD
  const int qblk = slot & 31;

  const int t = threadIdx.x;
  const int w = t >> 6, lane = t & 63;
  const int quad = lane >> 4, l16 = lane & 15;
  const int g = w >> 2;   // kv parity group
  const int ws = w & 3;   // q-pair index within group
  const int tq0 = qblk * 8 + ws * 2;

  __shared__ bf16_t Kst[2][8192];  // 16 KB per buffer (chunk pair)
  __shared__ bf16_t Vst[2][8192];  // 16 KB per buffer

  const size_t hb = (size_t)h * 256 * 1024;  // head base in tiled layouts

  union V8 {
    bf16x8 v8;
    bf16x4 v4[2];
  };

  // persistent Q B-frags (two q-tiles per wave)
  bf16x8 qa[2][2];
#pragma unroll
  for (int qt = 0; qt < 2; qt++)
#pragma unroll
    for (int kc = 0; kc < 2; kc++)
      qa[qt][kc] = *(const bf16x8*)(Qt + hb + (size_t)(tq0 + qt) * 1024 +
                                    kc * 512 + lane * 8);

  // stage chunk pair `mc` (chunks 2mc, 2mc+1): K,K then V,V (order matters
  // for the counted vmcnt waits).
#define STAGE(mc_, buf_)                                                      \
  {                                                                           \
    const size_t pb_ = hb + (size_t)(mc_) * 8192;                             \
    async_copy16(Kt + pb_ + (size_t)t * 8, (char*)&Kst[buf_][0] + w * 1024);  \
    async_copy16(Kt + pb_ + 4096 + (size_t)t * 8,                             \
                 (char*)&Kst[buf_][0] + 8192 + w * 1024);                     \
    async_copy16(Vt + pb_ + (size_t)t * 8, (char*)&Vst[buf_][0] + w * 1024);  \
    async_copy16(Vt + pb_ + 4096 + (size_t)t * 8,                             \
                 (char*)&Vst[buf_][0] + 8192 + w * 1024);                     \
  }

  f32x4 oT[2][4] = {};  // [qt][dkt]
  float ls[2] = {0.f, 0.f};
  const int laneK = lane * 16;
  V8 pb[2][2];

  // phase A body: K reads + QK + softmax (fills pb, ls)
#define PHASE_A(buf_)                                                         \
  {                                                                           \
    const char* Kc = (const char*)&Kst[buf_][0] + g * 8192;                   \
    f32x4 sT[2][4];                                                           \
    __builtin_amdgcn_s_setprio(1);                                            \
    _Pragma("unroll") for (int tt = 0; tt < 4; tt++) {                        \
      const bf16x8 k0 = *(const bf16x8*)(Kc + tt * 2048 + laneK);             \
      const bf16x8 k1 = *(const bf16x8*)(Kc + tt * 2048 + 1024 + laneK);      \
      _Pragma("unroll") for (int qt = 0; qt < 2; qt++) {                      \
        f32x4 z = {0.f, 0.f, 0.f, 0.f};                                       \
        z = MFMA_BF16(k0, qa[qt][0], z, 0, 0, 0);                             \
        z = MFMA_BF16(k1, qa[qt][1], z, 0, 0, 0);                             \
        sT[qt][tt] = z;                                                       \
      }                                                                       \
    }                                                                         \
    __builtin_amdgcn_s_setprio(0);                                            \
    _Pragma("unroll") for (int qt = 0; qt < 2; qt++) {                        \
      _Pragma("unroll") for (int tt = 0; tt < 4; tt++) {                      \
        bf16x4 pk;                                                            \
        float rs = 0.f;                                                       \
        _Pragma("unroll") for (int r = 0; r < 4; r++) {                       \
          const float pv = __builtin_amdgcn_exp2f(sT[qt][tt][r]);             \
          rs += pv;                                                           \
          pk[r] = (bf16_t)pv;                                                 \
        }                                                                     \
        ls[qt] += rs;                                                         \
        pb[qt][tt >> 1].v4[tt & 1] = pk;                                      \
      }                                                                       \
    }                                                                         \
  }

  // phase B body: V reads + PV
#define PHASE_B(buf_)                                                         \
  {                                                                           \
    const char* Vc = (const char*)&Vst[buf_][0] + g * 8192;                   \
    __builtin_amdgcn_s_setprio(1);                                            \
    _Pragma("unroll") for (int dkt = 0; dkt < 4; dkt++) {                     \
      _Pragma("unroll") for (int kvc = 0; kvc < 2; kvc++) {                   \
        const bf16x8 vv =                                                     \
            *(const bf16x8*)(Vc + dkt * 2048 + kvc * 1024 + laneK);           \
        _Pragma("unroll") for (int qt = 0; qt < 2; qt++)                      \
            oT[qt][dkt] = MFMA_BF16(vv, pb[qt][kvc].v8, oT[qt][dkt], 0, 0, 0);\
      }                                                                       \
    }                                                                         \
    __builtin_amdgcn_s_setprio(0);                                            \
  }

  STAGE(0, 0);

  const int NMC = L / 128;  // 32 macro-iters
  for (int mc = 0; mc < NMC - 1; mc++) {
    const int buf = mc & 1;
    asm volatile("s_waitcnt vmcnt(2)" ::: "memory");
    __builtin_amdgcn_s_barrier();
    __builtin_amdgcn_sched_barrier(0);
    STAGE(mc + 1, buf ^ 1);
    PHASE_A(buf);
    asm volatile("s_waitcnt vmcnt(4)" ::: "memory");
    __builtin_amdgcn_s_barrier();
    __builtin_amdgcn_sched_barrier(0);
    PHASE_B(buf);
  }
  {  // peeled last iteration: drain to 0 before the V reads
    const int buf = (NMC - 1) & 1;
    asm volatile("s_waitcnt vmcnt(2)" ::: "memory");
    __builtin_amdgcn_s_barrier();
    __builtin_amdgcn_sched_barrier(0);
    PHASE_A(buf);
    asm volatile("s_waitcnt vmcnt(0)" ::: "memory");
    __builtin_amdgcn_s_barrier();
    __builtin_amdgcn_sched_barrier(0);
    PHASE_B(buf);
  }
#undef STAGE
#undef PHASE_A
#undef PHASE_B

  // cross-group combine: g=1 waves hand partial (oT, ls) to matching g=0
  // wave via LDS scratch (qt0 in Kst, qt1 in Vst; stride 20 floats).
  __syncthreads();
  float* sc0 = (float*)&Kst[0][0];
  float* sc1 = (float*)&Vst[0][0];
  const int sidx = (ws * 64 + lane) * 20;
  if (g == 1) {
#pragma unroll
    for (int dkt = 0; dkt < 4; dkt++) {
      *(f32x4*)(sc0 + sidx + dkt * 4) = oT[0][dkt];
      *(f32x4*)(sc1 + sidx + dkt * 4) = oT[1][dkt];
    }
    sc0[sidx + 16] = ls[0];
    sc1[sidx + 16] = ls[1];
  }
  __syncthreads();
  if (g == 0) {
#pragma unroll
    for (int dkt = 0; dkt < 4; dkt++) {
      oT[0][dkt] += *(const f32x4*)(sc0 + sidx + dkt * 4);
      oT[1][dkt] += *(const f32x4*)(sc1 + sidx + dkt * 4);
    }
    ls[0] += sc0[sidx + 16];
    ls[1] += sc1[sidx + 16];

#pragma unroll
    for (int qt = 0; qt < 2; qt++) {
      float l = ls[qt];
      l += __shfl_xor(l, 16);
      l += __shfl_xor(l, 32);
      const float inv = 1.0f / l;
      const size_t row = (size_t)(tq0 + qt) * 16 + l16;
#pragma unroll
      for (int dkt = 0; dkt < 4; dkt++) {
        bf16x4 ov;
#pragma unroll
        for (int r = 0; r < 4; r++) ov[r] = (bf16_t)(oT[qt][dkt][r] * inv);
        *(bf16x4*)(O + row * 1024 + h * 64 + dkt * 16 + quad * 4) = ov;
      }
    }
  }
}

// ---------------------------------------------------------------------------
extern "C" void kernel_launch(void* const* d_in, const int* in_sizes, int n_in,
                              void* d_out, int out_size, void* d_ws,
                              size_t ws_size, hipStream_t stream) {
  const float* q  = (const float*)d_in[0];
  const float* k  = (const float*)d_in[1];
  const float* v  = (const float*)d_in[2];
  const float* wq = (const float*)d_in[3];
  const float* bq = (const float*)d_in[4];
  const float* wk = (const float*)d_in[5];
  const float* bk = (const float*)d_in[6];
  const float* wv = (const float*)d_in[7];
  const float* bv = (const float*)d_in[8];
  const float* wo = (const float*)d_in[9];
  const float* bo = (const float*)d_in[10];
  float* out = (float*)d_out;

  const int L = 4096, D = 1024;
  const int nLD = L * D;  // 4M
  const int nDD = D * D;  // 1M
  bf16_t* p = (bf16_t*)d_ws;
  bf16_t* qb  = p; p += nLD;
  bf16_t* kb  = p; p += nLD;
  bf16_t* vb  = p; p += nLD;
  bf16_t* wqb = p; p += nDD;
  bf16_t* wkb = p; p += nDD;
  bf16_t* wvb = p; p += nDD;
  bf16_t* wob = p; p += nDD;
  bf16_t* Op  = p; p += nLD;
  bf16_t* Qt  = p; p += nLD;
  bf16_t* Kt  = p; p += nLD;
  bf16_t* Vt  = p; p += nLD;

  dim3 blk(256);
  cast_f32_bf16<<<dim3(nLD / (256 * 8), 1, 7), blk, 0, stream>>>(
      q, qb, nLD, k, kb, nLD, v, vb, nLD, wq, wqb, nDD, wk, wkb, nDD,
      wv, wvb, nDD, wo, wob, nDD);
  gemm_qkv<<<dim3(L / 128, D / 128, 3), blk, 0, stream>>>(
      qb, wqb, bq, Qt, kb, wkb, bk, Kt, vb, wvb, bv, Vt, L, D, D);
  flash_attn<<<dim3((L / 128) * 16), dim3(512), 0, stream>>>(Qt, Kt, Vt, Op, L);
  gemm_out<<<dim3(L / 64, D / 128), blk, 0, stream>>>(Op, wob, bo, out, L, D,
                                                      D);
}

// Round 12
// 237.259 us; speedup vs baseline: 1.0457x; 1.0457x over previous
//
#include <hip/hip_runtime.h>
#include <hip/hip_bf16.h>
#include <stdint.h>

// MHA: B=1, L=4096, D=1024, H=16, dk=64.
// Inputs fp32, OUTPUT fp32. Internal compute bf16 with fp32 accumulation.
//
// v14:
//  - GEMMs: TRIPLE-buffered LDS + counted vmcnt (never 0 in-loop).  The
//    dbuf schedule (v12/v13) gave copies only ONE short compute phase
//    (~250cyc of 16 MFMA) to cover ~500-900cyc L2 latency -> per-iter time
//    was latency-bound and TILE-INDEPENDENT (explains v12==v13 neutral).
//    Now STAGE(i+2) is issued each iter; vmcnt(4) [qkv] / vmcnt(3) [out]
//    at iter top drains STAGE(i) (issued TWO compute phases ago) while
//    STAGE(i+1) stays in flight.  Last iter peeled with vmcnt(0) (the
//    counted wait would be a no-op there).
//  - flash: EXACT v9 (77.7us best).  cast: unchanged.  Control.

typedef __bf16 bf16_t;
typedef __bf16 bf16x8 __attribute__((ext_vector_type(8)));
typedef __bf16 bf16x4 __attribute__((ext_vector_type(4)));
typedef float f32x4 __attribute__((ext_vector_type(4)));
typedef unsigned short u16x8 __attribute__((ext_vector_type(8)));

#define MFMA_BF16 __builtin_amdgcn_mfma_f32_16x16x32_bf16

__device__ __forceinline__ void async_copy16(const void* g, void* lds) {
  __builtin_amdgcn_global_load_lds(
      (__attribute__((address_space(1))) void*)(uintptr_t)g,
      (__attribute__((address_space(3))) void*)lds, 16, 0, 0);
}

// ---------------------------------------------------------------------------
// fp32 -> bf16 cast, 8 elems/thread, z selects tensor.
// ---------------------------------------------------------------------------
__global__ __launch_bounds__(256) void cast_f32_bf16(
    const float* __restrict__ s0, bf16_t* __restrict__ d0, int n0,
    const float* __restrict__ s1, bf16_t* __restrict__ d1, int n1,
    const float* __restrict__ s2, bf16_t* __restrict__ d2, int n2,
    const float* __restrict__ s3, bf16_t* __restrict__ d3, int n3,
    const float* __restrict__ s4, bf16_t* __restrict__ d4, int n4,
    const float* __restrict__ s5, bf16_t* __restrict__ d5, int n5,
    const float* __restrict__ s6, bf16_t* __restrict__ d6, int n6) {
  const float* s;
  bf16_t* d;
  int n;
  switch (blockIdx.z) {
    case 0: s = s0; d = d0; n = n0; break;
    case 1: s = s1; d = d1; n = n1; break;
    case 2: s = s2; d = d2; n = n2; break;
    case 3: s = s3; d = d3; n = n3; break;
    case 4: s = s4; d = d4; n = n4; break;
    case 5: s = s5; d = d5; n = n5; break;
    default: s = s6; d = d6; n = n6; break;
  }
  const int i = (blockIdx.x * 256 + threadIdx.x) * 8;
  if (i >= n) return;
  float4 a = *(const float4*)(s + i);
  float4 b = *(const float4*)(s + i + 4);
  bf16x8 o;
  o[0] = (bf16_t)a.x; o[1] = (bf16_t)a.y; o[2] = (bf16_t)a.z; o[3] = (bf16_t)a.w;
  o[4] = (bf16_t)b.x; o[5] = (bf16_t)b.y; o[6] = (bf16_t)b.z; o[7] = (bf16_t)b.w;
  *(bf16x8*)(d + i) = o;
}

// ---------------------------------------------------------------------------
// QKV projection GEMM, tile 128x128, BK=32, 4 waves 2x2, TRIPLE-buffered
// LDS (3 x 16KB) with counted vmcnt: STAGE(i+2) issued each iter, vmcnt(4)
// at iter top drains STAGE(i) (2 compute phases old) while STAGE(i+1) (4
// copies) stays in flight.  Last iter peeled with vmcnt(0).
// z=0 -> Qt (scaled), z=1 -> Kt, z=2 -> Vt (transposed+P-packet-permuted).
// Epilogue (R6-verified): acc -> 32KB LDS image (reuses buffers 0-1 after
// a barrier) -> 8 linear dwordx4 passes into the 2 contiguous 16KB regions.
// ---------------------------------------------------------------------------
__global__ __launch_bounds__(256) void gemm_qkv(
    const bf16_t* __restrict__ A0, const bf16_t* __restrict__ W0,
    const float* __restrict__ b0, bf16_t* __restrict__ D0,
    const bf16_t* __restrict__ A1, const bf16_t* __restrict__ W1,
    const float* __restrict__ b1, bf16_t* __restrict__ D1,
    const bf16_t* __restrict__ A2, const bf16_t* __restrict__ W2,
    const float* __restrict__ b2, bf16_t* __restrict__ D2,
    int M, int N, int K) {
  const bf16_t *A, *W;
  const float* bias;
  bf16_t* D;
  const int zz = blockIdx.z;
  if (zz == 0)      { A = A0; W = W0; bias = b0; D = D0; }
  else if (zz == 1) { A = A1; W = W1; bias = b1; D = D1; }
  else              { A = A2; W = W2; bias = b2; D = D2; }

  // buffer b at smem + b*16384: A 128x32 (8KB) then B 128x32 (8KB).
  __shared__ __align__(16) char smem[49152];

  const int t = threadIdx.x;
  const int w = t >> 6, lane = t & 63;
  const int quad = lane >> 4, l16 = lane & 15;
  const int wr = w >> 1, wc = w & 1;
  const int m0 = blockIdx.x * 128;
  const int n0 = blockIdx.y * 128;
  const int srow = lane >> 2;
  const int scol = (lane & 3) * 8;

  f32x4 acc[4][4] = {};

#define GSTAGE(k0_, b_)                                                       \
  {                                                                           \
    char* base_ = (char*)smem + (b_) * 16384;                                 \
    async_copy16(&A[(size_t)(m0 + (2 * w) * 16 + srow) * K + (k0_) + scol],   \
                 base_ + (2 * w) * 1024);                                     \
    async_copy16(                                                             \
        &A[(size_t)(m0 + (2 * w + 1) * 16 + srow) * K + (k0_) + scol],        \
        base_ + (2 * w + 1) * 1024);                                          \
    async_copy16(&W[(size_t)(n0 + (2 * w) * 16 + srow) * K + (k0_) + scol],   \
                 base_ + 8192 + (2 * w) * 1024);                              \
    async_copy16(                                                             \
        &W[(size_t)(n0 + (2 * w + 1) * 16 + srow) * K + (k0_) + scol],        \
        base_ + 8192 + (2 * w + 1) * 1024);                                   \
  }

  GSTAGE(0, 0);
  GSTAGE(32, 1);

  const int NIT = K / 32;  // 32
  for (int i = 0; i < NIT; i++) {
    const int b = i % 3;
    if (i + 1 < NIT) {
      // STAGE(i) is 2 compute phases old; STAGE(i+1)'s 4 copies in flight.
      asm volatile("s_waitcnt vmcnt(4)" ::: "memory");
    } else {
      asm volatile("s_waitcnt vmcnt(0)" ::: "memory");
    }
    __builtin_amdgcn_s_barrier();
    __builtin_amdgcn_sched_barrier(0);
    if (i + 2 < NIT) GSTAGE((i + 2) * 32, (i + 2) % 3);

    const bf16_t(*As)[32] =
        reinterpret_cast<const bf16_t(*)[32]>(smem + b * 16384);
    const bf16_t(*Bs)[32] =
        reinterpret_cast<const bf16_t(*)[32]>(smem + b * 16384 + 8192);

    bf16x8 af[4], bfr[4];
#pragma unroll
    for (int mt = 0; mt < 4; mt++)
      af[mt] = *(const bf16x8*)&As[wr * 64 + mt * 16 + l16][quad * 8];
#pragma unroll
    for (int nt = 0; nt < 4; nt++)
      bfr[nt] = *(const bf16x8*)&Bs[wc * 64 + nt * 16 + l16][quad * 8];
#pragma unroll
    for (int mt = 0; mt < 4; mt++)
#pragma unroll
      for (int nt = 0; nt < 4; nt++)
        acc[mt][nt] = MFMA_BF16(af[mt], bfr[nt], acc[mt][nt], 0, 0, 0);
  }
#undef GSTAGE
  __syncthreads();  // all waves done reading all buffers before Ep overwrite

  // ---- epilogue: dump acc into 32KB LDS image (frag-granule order) ----
  bf16_t* Ep = (bf16_t*)smem;  // [wc][granule 0..7][1024]
  if (zz < 2) {
    const float qs = (zz == 0) ? 0.125f * 1.44269504088896340736f : 1.0f;
#pragma unroll
    for (int nt = 0; nt < 4; nt++) {
      const int col = n0 + wc * 64 + nt * 16 + l16;
      const float bb = bias[col];
      // dk = nt*16 + l16
      const int igb = ((nt >> 1) * 64 + ((2 * nt + (l16 >> 3)) & 3) * 16) * 8 +
                      (l16 & 7);
#pragma unroll
      for (int mt = 0; mt < 4; mt++) {
        const int gr = wc * 8 + wr * 4 + mt;  // LDS granule
#pragma unroll
        for (int r = 0; r < 4; r++) {
          Ep[gr * 1024 + igb + (quad * 4 + r) * 8] =
              (bf16_t)((acc[mt][nt][r] + bb) * qs);
        }
      }
    }
  } else {
#pragma unroll
    for (int nt = 0; nt < 4; nt++) {
      const int col = n0 + wc * 64 + nt * 16 + l16;
      const float bb = bias[col];
#pragma unroll
      for (int mt = 0; mt < 4; mt++) {
        const int gr = wc * 8 + wr * 4 + nt;  // V granule: (kvchunk=wr, dkt=nt)
        const int ig = ((mt >> 1) * 64 + quad * 16 + l16) * 8 + ((mt & 1) << 2);
        bf16x4 pk;
#pragma unroll
        for (int r = 0; r < 4; r++) pk[r] = (bf16_t)(acc[mt][nt][r] + bb);
        *(bf16x4*)&Ep[gr * 1024 + ig] = pk;
      }
    }
  }
  __syncthreads();

  // ---- linear copy: 2 contiguous 16KB regions, 16B/lane coalesced ----
  const int hh0 = n0 >> 6;
  const size_t gb = (zz < 2) ? (size_t)(m0 >> 4) : (size_t)(m0 >> 6) * 4;
#pragma unroll
  for (int p = 0; p < 8; p++) {
    const int f = (p * 256 + t) * 8;       // elem index in Ep
    const int wcr = f >> 13;               // region (head-half)
    const int off = f & 8191;              // elem within region
    const float4 vv = *(const float4*)&Ep[f];
    *(float4*)(D + ((size_t)(hh0 + wcr) * 256 + gb) * 1024 + off) = vv;
  }
}

// ---------------------------------------------------------------------------
// Output GEMM: C = A @ W^T + b (fp32 out).  Tile 64x128, TRIPLE-buffered
// (3 x 12KB) with counted vmcnt(3); last iter peeled with vmcnt(0).
// ---------------------------------------------------------------------------
__global__ __launch_bounds__(256) void gemm_out(
    const bf16_t* __restrict__ A, const bf16_t* __restrict__ W,
    const float* __restrict__ bias, float* __restrict__ C, int M, int N,
    int K) {
  __shared__ __align__(16) char smem[36864];

  const int t = threadIdx.x;
  const int w = t >> 6, lane = t & 63;
  const int quad = lane >> 4, l16 = lane & 15;
  const int wr = w >> 1, wc = w & 1;
  const int m0 = blockIdx.x * 64;
  const int n0 = blockIdx.y * 128;
  const int srow = t >> 2;
  const int scol = (t & 3) * 8;

  f32x4 acc[2][4] = {};

#define GSTAGE(k0_, b_)                                                     \
  {                                                                         \
    async_copy16(&A[(size_t)(m0 + srow) * K + (k0_) + scol],                \
                 (char*)smem + (b_) * 12288 + t * 16);                      \
    async_copy16(&W[(size_t)(n0 + srow) * K + (k0_) + scol],                \
                 (char*)smem + (b_) * 12288 + 4096 + t * 16);               \
    async_copy16(&W[(size_t)(n0 + 64 + srow) * K + (k0_) + scol],           \
                 (char*)smem + (b_) * 12288 + 8192 + t * 16);               \
  }

  GSTAGE(0, 0);
  GSTAGE(32, 1);

  const int NIT = K / 32;
  for (int i = 0; i < NIT; i++) {
    const int b = i % 3;
    if (i + 1 < NIT) {
      asm volatile("s_waitcnt vmcnt(3)" ::: "memory");
    } else {
      asm volatile("s_waitcnt vmcnt(0)" ::: "memory");
    }
    __builtin_amdgcn_s_barrier();
    __builtin_amdgcn_sched_barrier(0);
    if (i + 2 < NIT) GSTAGE((i + 2) * 32, (i + 2) % 3);

    const bf16_t(*As)[32] =
        reinterpret_cast<const bf16_t(*)[32]>(smem + b * 12288);
    const bf16_t(*Bs)[32] =
        reinterpret_cast<const bf16_t(*)[32]>(smem + b * 12288 + 4096);

    bf16x8 af[2], bfr[4];
#pragma unroll
    for (int mt = 0; mt < 2; mt++)
      af[mt] = *(const bf16x8*)&As[wr * 32 + mt * 16 + l16][quad * 8];
#pragma unroll
    for (int nt = 0; nt < 4; nt++)
      bfr[nt] = *(const bf16x8*)&Bs[wc * 64 + nt * 16 + l16][quad * 8];
#pragma unroll
    for (int mt = 0; mt < 2; mt++)
#pragma unroll
      for (int nt = 0; nt < 4; nt++)
        acc[mt][nt] = MFMA_BF16(af[mt], bfr[nt], acc[mt][nt], 0, 0, 0);
  }
#undef GSTAGE

#pragma unroll
  for (int nt = 0; nt < 4; nt++) {
    const int col = n0 + wc * 64 + nt * 16 + l16;
    const float bb = bias[col];
#pragma unroll
    for (int mt = 0; mt < 2; mt++) {
#pragma unroll
      for (int r = 0; r < 4; r++) {
        const int row = m0 + wr * 32 + mt * 16 + quad * 4 + r;
        C[(size_t)row * N + col] = acc[mt][nt][r] + bb;
      }
    }
  }
}

// ---------------------------------------------------------------------------
// Flash v9 (EXACT — best measured 77.7us).  8 waves, kv-parity split, Nq=2,
// in-register P, two-phase counted-vmcnt schedule:
//   phase A: s_waitcnt vmcnt(2) [own K(i) landed] ; s_barrier ;
//            STAGE(i+1) ; read K ; QK MFMAs (setprio) ; softmax -> pb regs
//   phase B: s_waitcnt vmcnt(4) [own V(i) landed] ; s_barrier ;
//            read V ; PV MFMAs (setprio)
// Prefetch for iter i+1 stays IN FLIGHT across both barriers; last iter
// peeled for the final drain.
// ---------------------------------------------------------------------------
__global__ __launch_bounds__(512, 4) void flash_attn(
    const bf16_t* __restrict__ Qt, const bf16_t* __restrict__ Kt,
    const bf16_t* __restrict__ Vt, bf16_t* __restrict__ O, int L) {
  // linear block id lands on XCD i%8 (round-robin dispatch): 2 heads/XCD.
  const int i = blockIdx.x;
  const int slot = i >> 3;                  // 0..63 within XCD
  const int h = (i & 7) * 2 + (slot >> 5);  // 2 heads per XCD
  const int qblk = slot & 31;

  const int t = threadIdx.x;
  const int w = t >> 6, lane = t & 63;
  const int quad = lane >> 4, l16 = lane & 15;
  const int g = w >> 2;   // kv parity group
  const int ws = w & 3;   // q-pair index within group
  const int tq0 = qblk * 8 + ws * 2;

  __shared__ bf16_t Kst[2][8192];  // 16 KB per buffer (chunk pair)
  __shared__ bf16_t Vst[2][8192];  // 16 KB per buffer

  const size_t hb = (size_t)h * 256 * 1024;  // head base in tiled layouts

  union V8 {
    bf16x8 v8;
    bf16x4 v4[2];
  };

  // persistent Q B-frags (two q-tiles per wave)
  bf16x8 qa[2][2];
#pragma unroll
  for (int qt = 0; qt < 2; qt++)
#pragma unroll
    for (int kc = 0; kc < 2; kc++)
      qa[qt][kc] = *(const bf16x8*)(Qt + hb + (size_t)(tq0 + qt) * 1024 +
                                    kc * 512 + lane * 8);

  // stage chunk pair `mc` (chunks 2mc, 2mc+1): K,K then V,V (order matters
  // for the counted vmcnt waits).
#define STAGE(mc_, buf_)                                                      \
  {                                                                           \
    const size_t pb_ = hb + (size_t)(mc_) * 8192;                             \
    async_copy16(Kt + pb_ + (size_t)t * 8, (char*)&Kst[buf_][0] + w * 1024);  \
    async_copy16(Kt + pb_ + 4096 + (size_t)t * 8,                             \
                 (char*)&Kst[buf_][0] + 8192 + w * 1024);                     \
    async_copy16(Vt + pb_ + (size_t)t * 8, (char*)&Vst[buf_][0] + w * 1024);  \
    async_copy16(Vt + pb_ + 4096 + (size_t)t * 8,                             \
                 (char*)&Vst[buf_][0] + 8192 + w * 1024);                     \
  }

  f32x4 oT[2][4] = {};  // [qt][dkt]
  float ls[2] = {0.f, 0.f};
  const int laneK = lane * 16;
  V8 pb[2][2];

  // phase A body: K reads + QK + softmax (fills pb, ls)
#define PHASE_A(buf_)                                                         \
  {                                                                           \
    const char* Kc = (const char*)&Kst[buf_][0] + g * 8192;                   \
    f32x4 sT[2][4];                                                           \
    __builtin_amdgcn_s_setprio(1);                                            \
    _Pragma("unroll") for (int tt = 0; tt < 4; tt++) {                        \
      const bf16x8 k0 = *(const bf16x8*)(Kc + tt * 2048 + laneK);             \
      const bf16x8 k1 = *(const bf16x8*)(Kc + tt * 2048 + 1024 + laneK);      \
      _Pragma("unroll") for (int qt = 0; qt < 2; qt++) {                      \
        f32x4 z = {0.f, 0.f, 0.f, 0.f};                                       \
        z = MFMA_BF16(k0, qa[qt][0], z, 0, 0, 0);                             \
        z = MFMA_BF16(k1, qa[qt][1], z, 0, 0, 0);                             \
        sT[qt][tt] = z;                                                       \
      }                                                                       \
    }                                                                         \
    __builtin_amdgcn_s_setprio(0);                                            \
    _Pragma("unroll") for (int qt = 0; qt < 2; qt++) {                        \
      _Pragma("unroll") for (int tt = 0; tt < 4; tt++) {                      \
        bf16x4 pk;                                                            \
        float rs = 0.f;                                                       \
        _Pragma("unroll") for (int r = 0; r < 4; r++) {                       \
          const float pv = __builtin_amdgcn_exp2f(sT[qt][tt][r]);             \
          rs += pv;                                                           \
          pk[r] = (bf16_t)pv;                                                 \
        }                                                                     \
        ls[qt] += rs;                                                         \
        pb[qt][tt >> 1].v4[tt & 1] = pk;                                      \
      }                                                                       \
    }                                                                         \
  }

  // phase B body: V reads + PV
#define PHASE_B(buf_)                                                         \
  {                                                                           \
    const char* Vc = (const char*)&Vst[buf_][0] + g * 8192;                   \
    __builtin_amdgcn_s_setprio(1);                                            \
    _Pragma("unroll") for (int dkt = 0; dkt < 4; dkt++) {                     \
      _Pragma("unroll") for (int kvc = 0; kvc < 2; kvc++) {                   \
        const bf16x8 vv =                                                     \
            *(const bf16x8*)(Vc + dkt * 2048 + kvc * 1024 + laneK);           \
        _Pragma("unroll") for (int qt = 0; qt < 2; qt++)                      \
            oT[qt][dkt] = MFMA_BF16(vv, pb[qt][kvc].v8, oT[qt][dkt], 0, 0, 0);\
      }                                                                       \
    }                                                                         \
    __builtin_amdgcn_s_setprio(0);                                            \
  }

  STAGE(0, 0);

  const int NMC = L / 128;  // 32 macro-iters
  for (int mc = 0; mc < NMC - 1; mc++) {
    const int buf = mc & 1;
    asm volatile("s_waitcnt vmcnt(2)" ::: "memory");
    __builtin_amdgcn_s_barrier();
    __builtin_amdgcn_sched_barrier(0);
    STAGE(mc + 1, buf ^ 1);
    PHASE_A(buf);
    asm volatile("s_waitcnt vmcnt(4)" ::: "memory");
    __builtin_amdgcn_s_barrier();
    __builtin_amdgcn_sched_barrier(0);
    PHASE_B(buf);
  }
  {  // peeled last iteration: drain to 0 before the V reads
    const int buf = (NMC - 1) & 1;
    asm volatile("s_waitcnt vmcnt(2)" ::: "memory");
    __builtin_amdgcn_s_barrier();
    __builtin_amdgcn_sched_barrier(0);
    PHASE_A(buf);
    asm volatile("s_waitcnt vmcnt(0)" ::: "memory");
    __builtin_amdgcn_s_barrier();
    __builtin_amdgcn_sched_barrier(0);
    PHASE_B(buf);
  }
#undef STAGE
#undef PHASE_A
#undef PHASE_B

  // cross-group combine: g=1 waves hand partial (oT, ls) to matching g=0
  // wave via LDS scratch (qt0 in Kst, qt1 in Vst; stride 20 floats).
  __syncthreads();
  float* sc0 = (float*)&Kst[0][0];
  float* sc1 = (float*)&Vst[0][0];
  const int sidx = (ws * 64 + lane) * 20;
  if (g == 1) {
#pragma unroll
    for (int dkt = 0; dkt < 4; dkt++) {
      *(f32x4*)(sc0 + sidx + dkt * 4) = oT[0][dkt];
      *(f32x4*)(sc1 + sidx + dkt * 4) = oT[1][dkt];
    }
    sc0[sidx + 16] = ls[0];
    sc1[sidx + 16] = ls[1];
  }
  __syncthreads();
  if (g == 0) {
#pragma unroll
    for (int dkt = 0; dkt < 4; dkt++) {
      oT[0][dkt] += *(const f32x4*)(sc0 + sidx + dkt * 4);
      oT[1][dkt] += *(const f32x4*)(sc1 + sidx + dkt * 4);
    }
    ls[0] += sc0[sidx + 16];
    ls[1] += sc1[sidx + 16];

#pragma unroll
    for (int qt = 0; qt < 2; qt++) {
      float l = ls[qt];
      l += __shfl_xor(l, 16);
      l += __shfl_xor(l, 32);
      const float inv = 1.0f / l;
      const size_t row = (size_t)(tq0 + qt) * 16 + l16;
#pragma unroll
      for (int dkt = 0; dkt < 4; dkt++) {
        bf16x4 ov;
#pragma unroll
        for (int r = 0; r < 4; r++) ov[r] = (bf16_t)(oT[qt][dkt][r] * inv);
        *(bf16x4*)(O + row * 1024 + h * 64 + dkt * 16 + quad * 4) = ov;
      }
    }
  }
}

// ---------------------------------------------------------------------------
extern "C" void kernel_launch(void* const* d_in, const int* in_sizes, int n_in,
                              void* d_out, int out_size, void* d_ws,
                              size_t ws_size, hipStream_t stream) {
  const float* q  = (const float*)d_in[0];
  const float* k  = (const float*)d_in[1];
  const float* v  = (const float*)d_in[2];
  const float* wq = (const float*)d_in[3];
  const float* bq = (const float*)d_in[4];
  const float* wk = (const float*)d_in[5];
  const float* bk = (const float*)d_in[6];
  const float* wv = (const float*)d_in[7];
  const float* bv = (const float*)d_in[8];
  const float* wo = (const float*)d_in[9];
  const float* bo = (const float*)d_in[10];
  float* out = (float*)d_out;

  const int L = 4096, D = 1024;
  const int nLD = L * D;  // 4M
  const int nDD = D * D;  // 1M
  bf16_t* p = (bf16_t*)d_ws;
  bf16_t* qb  = p; p += nLD;
  bf16_t* kb  = p; p += nLD;
  bf16_t* vb  = p; p += nLD;
  bf16_t* wqb = p; p += nDD;
  bf16_t* wkb = p; p += nDD;
  bf16_t* wvb = p; p += nDD;
  bf16_t* wob = p; p += nDD;
  bf16_t* Op  = p; p += nLD;
  bf16_t* Qt  = p; p += nLD;
  bf16_t* Kt  = p; p += nLD;
  bf16_t* Vt  = p; p += nLD;

  dim3 blk(256);
  cast_f32_bf16<<<dim3(nLD / (256 * 8), 1, 7), blk, 0, stream>>>(
      q, qb, nLD, k, kb, nLD, v, vb, nLD, wq, wqb, nDD, wk, wkb, nDD,
      wv, wvb, nDD, wo, wob, nDD);
  gemm_qkv<<<dim3(L / 128, D / 128, 3), blk, 0, stream>>>(
      qb, wqb, bq, Qt, kb, wkb, bk, Kt, vb, wvb, bv, Vt, L, D, D);
  flash_attn<<<dim3((L / 128) * 16), dim3(512), 0, stream>>>(Qt, Kt, Vt, Op, L);
  gemm_out<<<dim3(L / 64, D / 128), blk, 0, stream>>>(Op, wob, bo, out, L, D,
                                                      D);
}

// Round 13
// 235.972 us; speedup vs baseline: 1.0514x; 1.0055x over previous
//
#include <hip/hip_runtime.h>
#include <hip/hip_bf16.h>
#include <stdint.h>

// MHA: B=1, L=4096, D=1024, H=16, dk=64.
// Inputs fp32, OUTPUT fp32. Internal compute bf16 with fp32 accumulation.
//
// v15:
//  - GEMMs: BK=64, double-buffered, staged as TWO independently-counted
//    k-halves (each half a verbatim [128][32]-granule stage -> no new bank
//    conflicts).  Per-iter two phases, each: vmcnt(N) for the half issued a
//    FULL ITERATION ago (~550cyc coverage) -> barrier -> issue next half ->
//    16 MFMA.  This is flash-v9's proven two-phase counted schedule
//    transplanted; iterations halve (32->16), waits never drain prefetch.
//  - flash: EXACT v9 (77.7us best).  cast: unchanged.  Control.

typedef __bf16 bf16_t;
typedef __bf16 bf16x8 __attribute__((ext_vector_type(8)));
typedef __bf16 bf16x4 __attribute__((ext_vector_type(4)));
typedef float f32x4 __attribute__((ext_vector_type(4)));
typedef unsigned short u16x8 __attribute__((ext_vector_type(8)));

#define MFMA_BF16 __builtin_amdgcn_mfma_f32_16x16x32_bf16

__device__ __forceinline__ void async_copy16(const void* g, void* lds) {
  __builtin_amdgcn_global_load_lds(
      (__attribute__((address_space(1))) void*)(uintptr_t)g,
      (__attribute__((address_space(3))) void*)lds, 16, 0, 0);
}

// ---------------------------------------------------------------------------
// fp32 -> bf16 cast, 8 elems/thread, z selects tensor.
// ---------------------------------------------------------------------------
__global__ __launch_bounds__(256) void cast_f32_bf16(
    const float* __restrict__ s0, bf16_t* __restrict__ d0, int n0,
    const float* __restrict__ s1, bf16_t* __restrict__ d1, int n1,
    const float* __restrict__ s2, bf16_t* __restrict__ d2, int n2,
    const float* __restrict__ s3, bf16_t* __restrict__ d3, int n3,
    const float* __restrict__ s4, bf16_t* __restrict__ d4, int n4,
    const float* __restrict__ s5, bf16_t* __restrict__ d5, int n5,
    const float* __restrict__ s6, bf16_t* __restrict__ d6, int n6) {
  const float* s;
  bf16_t* d;
  int n;
  switch (blockIdx.z) {
    case 0: s = s0; d = d0; n = n0; break;
    case 1: s = s1; d = d1; n = n1; break;
    case 2: s = s2; d = d2; n = n2; break;
    case 3: s = s3; d = d3; n = n3; break;
    case 4: s = s4; d = d4; n = n4; break;
    case 5: s = s5; d = d5; n = n5; break;
    default: s = s6; d = d6; n = n6; break;
  }
  const int i = (blockIdx.x * 256 + threadIdx.x) * 8;
  if (i >= n) return;
  float4 a = *(const float4*)(s + i);
  float4 b = *(const float4*)(s + i + 4);
  bf16x8 o;
  o[0] = (bf16_t)a.x; o[1] = (bf16_t)a.y; o[2] = (bf16_t)a.z; o[3] = (bf16_t)a.w;
  o[4] = (bf16_t)b.x; o[5] = (bf16_t)b.y; o[6] = (bf16_t)b.z; o[7] = (bf16_t)b.w;
  *(bf16x8*)(d + i) = o;
}

// ---------------------------------------------------------------------------
// QKV projection GEMM, tile 128x128, BK=64 as two k-halves, 4 waves 2x2,
// dbuf (2 x 32KB).  Buffer layout: [A0 8K][A1 8K][B0 8K][B1 8K], each block
// a [128][32] granule image (same frag-read pattern as BK=32 -> no new
// conflicts).  Two phases/iter, each with counted vmcnt(4) for the half
// staged a full iteration earlier; last iter peeled to vmcnt(0).
// z=0 -> Qt (scaled), z=1 -> Kt, z=2 -> Vt (transposed+P-packet-permuted).
// Epilogue (R6-verified): acc -> 32KB LDS image -> 8 linear dwordx4 passes.
// ---------------------------------------------------------------------------
__global__ __launch_bounds__(256) void gemm_qkv(
    const bf16_t* __restrict__ A0, const bf16_t* __restrict__ W0,
    const float* __restrict__ b0, bf16_t* __restrict__ D0,
    const bf16_t* __restrict__ A1, const bf16_t* __restrict__ W1,
    const float* __restrict__ b1, bf16_t* __restrict__ D1,
    const bf16_t* __restrict__ A2, const bf16_t* __restrict__ W2,
    const float* __restrict__ b2, bf16_t* __restrict__ D2,
    int M, int N, int K) {
  const bf16_t *A, *W;
  const float* bias;
  bf16_t* D;
  const int zz = blockIdx.z;
  if (zz == 0)      { A = A0; W = W0; bias = b0; D = D0; }
  else if (zz == 1) { A = A1; W = W1; bias = b1; D = D1; }
  else              { A = A2; W = W2; bias = b2; D = D2; }

  __shared__ __align__(16) char smem[65536];

  const int t = threadIdx.x;
  const int w = t >> 6, lane = t & 63;
  const int quad = lane >> 4, l16 = lane & 15;
  const int wr = w >> 1, wc = w & 1;
  const int m0 = blockIdx.x * 128;
  const int n0 = blockIdx.y * 128;
  const int srow = lane >> 2;
  const int scol = (lane & 3) * 8;

  f32x4 acc[4][4] = {};

  // stage k-half h of k-step k0 into buffer b_: 4 copies (A_h 2, B_h 2).
#define GSTAGEH(k0_, h_, b_)                                                  \
  {                                                                           \
    char* ab_ = (char*)smem + (b_) * 32768 + (h_) * 8192;                     \
    char* bb_ = ab_ + 16384;                                                  \
    const int kc_ = (k0_) + (h_) * 32;                                        \
    async_copy16(&A[(size_t)(m0 + (2 * w) * 16 + srow) * K + kc_ + scol],     \
                 ab_ + (2 * w) * 1024);                                       \
    async_copy16(&A[(size_t)(m0 + (2 * w + 1) * 16 + srow) * K + kc_ + scol], \
                 ab_ + (2 * w + 1) * 1024);                                   \
    async_copy16(&W[(size_t)(n0 + (2 * w) * 16 + srow) * K + kc_ + scol],     \
                 bb_ + (2 * w) * 1024);                                       \
    async_copy16(&W[(size_t)(n0 + (2 * w + 1) * 16 + srow) * K + kc_ + scol], \
                 bb_ + (2 * w + 1) * 1024);                                   \
  }

  // compute k-half h from buffer b_: 16 MFMA.
#define GCOMP(h_, b_)                                                         \
  {                                                                           \
    const bf16_t(*As)[32] = reinterpret_cast<const bf16_t(*)[32]>(            \
        smem + (b_) * 32768 + (h_) * 8192);                                   \
    const bf16_t(*Bs)[32] = reinterpret_cast<const bf16_t(*)[32]>(            \
        smem + (b_) * 32768 + 16384 + (h_) * 8192);                           \
    bf16x8 af[4], bfr[4];                                                     \
    _Pragma("unroll") for (int mt = 0; mt < 4; mt++)                          \
        af[mt] = *(const bf16x8*)&As[wr * 64 + mt * 16 + l16][quad * 8];      \
    _Pragma("unroll") for (int nt = 0; nt < 4; nt++)                          \
        bfr[nt] = *(const bf16x8*)&Bs[wc * 64 + nt * 16 + l16][quad * 8];     \
    _Pragma("unroll") for (int mt = 0; mt < 4; mt++)                          \
        _Pragma("unroll") for (int nt = 0; nt < 4; nt++)                      \
            acc[mt][nt] = MFMA_BF16(af[mt], bfr[nt], acc[mt][nt], 0, 0, 0);   \
  }

  GSTAGEH(0, 0, 0);
  GSTAGEH(0, 1, 0);

  const int NIT = K / 64;  // 16
  for (int i = 0; i < NIT; i++) {
    const int b = i & 1;
    // phase 0: first-half of stage(i) is a full iteration old.
    asm volatile("s_waitcnt vmcnt(4)" ::: "memory");
    __builtin_amdgcn_s_barrier();
    __builtin_amdgcn_sched_barrier(0);
    if (i + 1 < NIT) GSTAGEH((i + 1) * 64, 0, b ^ 1);
    GCOMP(0, b);
    // phase 1: second-half of stage(i) is a full iteration old.
    if (i + 1 < NIT) {
      asm volatile("s_waitcnt vmcnt(4)" ::: "memory");
    } else {
      asm volatile("s_waitcnt vmcnt(0)" ::: "memory");
    }
    __builtin_amdgcn_s_barrier();
    __builtin_amdgcn_sched_barrier(0);
    if (i + 1 < NIT) GSTAGEH((i + 1) * 64, 1, b ^ 1);
    GCOMP(1, b);
  }
#undef GSTAGEH
#undef GCOMP
  __syncthreads();  // all waves done reading both buffers before Ep overwrite

  // ---- epilogue: dump acc into 32KB LDS image (frag-granule order) ----
  bf16_t* Ep = (bf16_t*)smem;  // [wc][granule 0..7][1024]
  if (zz < 2) {
    const float qs = (zz == 0) ? 0.125f * 1.44269504088896340736f : 1.0f;
#pragma unroll
    for (int nt = 0; nt < 4; nt++) {
      const int col = n0 + wc * 64 + nt * 16 + l16;
      const float bb = bias[col];
      // dk = nt*16 + l16
      const int igb = ((nt >> 1) * 64 + ((2 * nt + (l16 >> 3)) & 3) * 16) * 8 +
                      (l16 & 7);
#pragma unroll
      for (int mt = 0; mt < 4; mt++) {
        const int gr = wc * 8 + wr * 4 + mt;  // LDS granule
#pragma unroll
        for (int r = 0; r < 4; r++) {
          Ep[gr * 1024 + igb + (quad * 4 + r) * 8] =
              (bf16_t)((acc[mt][nt][r] + bb) * qs);
        }
      }
    }
  } else {
#pragma unroll
    for (int nt = 0; nt < 4; nt++) {
      const int col = n0 + wc * 64 + nt * 16 + l16;
      const float bb = bias[col];
#pragma unroll
      for (int mt = 0; mt < 4; mt++) {
        const int gr = wc * 8 + wr * 4 + nt;  // V granule: (kvchunk=wr, dkt=nt)
        const int ig = ((mt >> 1) * 64 + quad * 16 + l16) * 8 + ((mt & 1) << 2);
        bf16x4 pk;
#pragma unroll
        for (int r = 0; r < 4; r++) pk[r] = (bf16_t)(acc[mt][nt][r] + bb);
        *(bf16x4*)&Ep[gr * 1024 + ig] = pk;
      }
    }
  }
  __syncthreads();

  // ---- linear copy: 2 contiguous 16KB regions, 16B/lane coalesced ----
  const int hh0 = n0 >> 6;
  const size_t gb = (zz < 2) ? (size_t)(m0 >> 4) : (size_t)(m0 >> 6) * 4;
#pragma unroll
  for (int p = 0; p < 8; p++) {
    const int f = (p * 256 + t) * 8;       // elem index in Ep
    const int wcr = f >> 13;               // region (head-half)
    const int off = f & 8191;              // elem within region
    const float4 vv = *(const float4*)&Ep[f];
    *(float4*)(D + ((size_t)(hh0 + wcr) * 256 + gb) * 1024 + off) = vv;
  }
}

// ---------------------------------------------------------------------------
// Output GEMM: C = A @ W^T + b (fp32 out).  Tile 64x128, BK=64 two-phase
// counted schedule.  Buffer: [A0 4K][A1 4K][B0 8K][B1 8K] = 24KB, dbuf
// 48KB -> 3 blocks/CU.  Half = 3 copies (A 1, B 2) -> vmcnt(3).
// ---------------------------------------------------------------------------
__global__ __launch_bounds__(256) void gemm_out(
    const bf16_t* __restrict__ A, const bf16_t* __restrict__ W,
    const float* __restrict__ bias, float* __restrict__ C, int M, int N,
    int K) {
  __shared__ __align__(16) char smem[49152];

  const int t = threadIdx.x;
  const int w = t >> 6, lane = t & 63;
  const int quad = lane >> 4, l16 = lane & 15;
  const int wr = w >> 1, wc = w & 1;
  const int m0 = blockIdx.x * 64;
  const int n0 = blockIdx.y * 128;
  const int srow = t >> 2;
  const int scol = (t & 3) * 8;

  f32x4 acc[2][4] = {};

#define GSTAGEH(k0_, h_, b_)                                                \
  {                                                                         \
    char* base_ = (char*)smem + (b_) * 24576;                               \
    const int kc_ = (k0_) + (h_) * 32;                                      \
    async_copy16(&A[(size_t)(m0 + srow) * K + kc_ + scol],                  \
                 base_ + (h_) * 4096 + t * 16);                             \
    async_copy16(&W[(size_t)(n0 + srow) * K + kc_ + scol],                  \
                 base_ + 8192 + (h_) * 8192 + t * 16);                      \
    async_copy16(&W[(size_t)(n0 + 64 + srow) * K + kc_ + scol],             \
                 base_ + 8192 + (h_) * 8192 + 4096 + t * 16);               \
  }

#define GCOMP(h_, b_)                                                       \
  {                                                                         \
    const bf16_t(*As)[32] = reinterpret_cast<const bf16_t(*)[32]>(          \
        smem + (b_) * 24576 + (h_) * 4096);                                 \
    const bf16_t(*Bs)[32] = reinterpret_cast<const bf16_t(*)[32]>(          \
        smem + (b_) * 24576 + 8192 + (h_) * 8192);                          \
    bf16x8 af[2], bfr[4];                                                   \
    _Pragma("unroll") for (int mt = 0; mt < 2; mt++)                        \
        af[mt] = *(const bf16x8*)&As[wr * 32 + mt * 16 + l16][quad * 8];    \
    _Pragma("unroll") for (int nt = 0; nt < 4; nt++)                        \
        bfr[nt] = *(const bf16x8*)&Bs[wc * 64 + nt * 16 + l16][quad * 8];   \
    _Pragma("unroll") for (int mt = 0; mt < 2; mt++)                        \
        _Pragma("unroll") for (int nt = 0; nt < 4; nt++)                    \
            acc[mt][nt] = MFMA_BF16(af[mt], bfr[nt], acc[mt][nt], 0, 0, 0); \
  }

  GSTAGEH(0, 0, 0);
  GSTAGEH(0, 1, 0);

  const int NIT = K / 64;  // 16
  for (int i = 0; i < NIT; i++) {
    const int b = i & 1;
    asm volatile("s_waitcnt vmcnt(3)" ::: "memory");
    __builtin_amdgcn_s_barrier();
    __builtin_amdgcn_sched_barrier(0);
    if (i + 1 < NIT) GSTAGEH((i + 1) * 64, 0, b ^ 1);
    GCOMP(0, b);
    if (i + 1 < NIT) {
      asm volatile("s_waitcnt vmcnt(3)" ::: "memory");
    } else {
      asm volatile("s_waitcnt vmcnt(0)" ::: "memory");
    }
    __builtin_amdgcn_s_barrier();
    __builtin_amdgcn_sched_barrier(0);
    if (i + 1 < NIT) GSTAGEH((i + 1) * 64, 1, b ^ 1);
    GCOMP(1, b);
  }
#undef GSTAGEH
#undef GCOMP

#pragma unroll
  for (int nt = 0; nt < 4; nt++) {
    const int col = n0 + wc * 64 + nt * 16 + l16;
    const float bb = bias[col];
#pragma unroll
    for (int mt = 0; mt < 2; mt++) {
#pragma unroll
      for (int r = 0; r < 4; r++) {
        const int row = m0 + wr * 32 + mt * 16 + quad * 4 + r;
        C[(size_t)row * N + col] = acc[mt][nt][r] + bb;
      }
    }
  }
}

// ---------------------------------------------------------------------------
// Flash v9 (EXACT — best measured 77.7us).  8 waves, kv-parity split, Nq=2,
// in-register P, two-phase counted-vmcnt schedule:
//   phase A: s_waitcnt vmcnt(2) [own K(i) landed] ; s_barrier ;
//            STAGE(i+1) ; read K ; QK MFMAs (setprio) ; softmax -> pb regs
//   phase B: s_waitcnt vmcnt(4) [own V(i) landed] ; s_barrier ;
//            read V ; PV MFMAs (setprio)
// Prefetch for iter i+1 stays IN FLIGHT across both barriers; last iter
// peeled for the final drain.
// ---------------------------------------------------------------------------
__global__ __launch_bounds__(512, 4) void flash_attn(
    const bf16_t* __restrict__ Qt, const bf16_t* __restrict__ Kt,
    const bf16_t* __restrict__ Vt, bf16_t* __restrict__ O, int L) {
  // linear block id lands on XCD i%8 (round-robin dispatch): 2 heads/XCD.
  const int i = blockIdx.x;
  const int slot = i >> 3;                  // 0..63 within XCD
  const int h = (i & 7) * 2 + (slot >> 5);  // 2 heads per XCD
  const int qblk = slot & 31;

  const int t = threadIdx.x;
  const int w = t >> 6, lane = t & 63;
  const int quad = lane >> 4, l16 = lane & 15;
  const int g = w >> 2;   // kv parity group
  const int ws = w & 3;   // q-pair index within group
  const int tq0 = qblk * 8 + ws * 2;

  __shared__ bf16_t Kst[2][8192];  // 16 KB per buffer (chunk pair)
  __shared__ bf16_t Vst[2][8192];  // 16 KB per buffer

  const size_t hb = (size_t)h * 256 * 1024;  // head base in tiled layouts

  union V8 {
    bf16x8 v8;
    bf16x4 v4[2];
  };

  // persistent Q B-frags (two q-tiles per wave)
  bf16x8 qa[2][2];
#pragma unroll
  for (int qt = 0; qt < 2; qt++)
#pragma unroll
    for (int kc = 0; kc < 2; kc++)
      qa[qt][kc] = *(const bf16x8*)(Qt + hb + (size_t)(tq0 + qt) * 1024 +
                                    kc * 512 + lane * 8);

  // stage chunk pair `mc` (chunks 2mc, 2mc+1): K,K then V,V (order matters
  // for the counted vmcnt waits).
#define STAGE(mc_, buf_)                                                      \
  {                                                                           \
    const size_t pb_ = hb + (size_t)(mc_) * 8192;                             \
    async_copy16(Kt + pb_ + (size_t)t * 8, (char*)&Kst[buf_][0] + w * 1024);  \
    async_copy16(Kt + pb_ + 4096 + (size_t)t * 8,                             \
                 (char*)&Kst[buf_][0] + 8192 + w * 1024);                     \
    async_copy16(Vt + pb_ + (size_t)t * 8, (char*)&Vst[buf_][0] + w * 1024);  \
    async_copy16(Vt + pb_ + 4096 + (size_t)t * 8,                             \
                 (char*)&Vst[buf_][0] + 8192 + w * 1024);                     \
  }

  f32x4 oT[2][4] = {};  // [qt][dkt]
  float ls[2] = {0.f, 0.f};
  const int laneK = lane * 16;
  V8 pb[2][2];

  // phase A body: K reads + QK + softmax (fills pb, ls)
#define PHASE_A(buf_)                                                         \
  {                                                                           \
    const char* Kc = (const char*)&Kst[buf_][0] + g * 8192;                   \
    f32x4 sT[2][4];                                                           \
    __builtin_amdgcn_s_setprio(1);                                            \
    _Pragma("unroll") for (int tt = 0; tt < 4; tt++) {                        \
      const bf16x8 k0 = *(const bf16x8*)(Kc + tt * 2048 + laneK);             \
      const bf16x8 k1 = *(const bf16x8*)(Kc + tt * 2048 + 1024 + laneK);      \
      _Pragma("unroll") for (int qt = 0; qt < 2; qt++) {                      \
        f32x4 z = {0.f, 0.f, 0.f, 0.f};                                       \
        z = MFMA_BF16(k0, qa[qt][0], z, 0, 0, 0);                             \
        z = MFMA_BF16(k1, qa[qt][1], z, 0, 0, 0);                             \
        sT[qt][tt] = z;                                                       \
      }                                                                       \
    }                                                                         \
    __builtin_amdgcn_s_setprio(0);                                            \
    _Pragma("unroll") for (int qt = 0; qt < 2; qt++) {                        \
      _Pragma("unroll") for (int tt = 0; tt < 4; tt++) {                      \
        bf16x4 pk;                                                            \
        float rs = 0.f;                                                       \
        _Pragma("unroll") for (int r = 0; r < 4; r++) {                       \
          const float pv = __builtin_amdgcn_exp2f(sT[qt][tt][r]);             \
          rs += pv;                                                           \
          pk[r] = (bf16_t)pv;                                                 \
        }                                                                     \
        ls[qt] += rs;                                                         \
        pb[qt][tt >> 1].v4[tt & 1] = pk;                                      \
      }                                                                       \
    }                                                                         \
  }

  // phase B body: V reads + PV
#define PHASE_B(buf_)                                                         \
  {                                                                           \
    const char* Vc = (const char*)&Vst[buf_][0] + g * 8192;                   \
    __builtin_amdgcn_s_setprio(1);                                            \
    _Pragma("unroll") for (int dkt = 0; dkt < 4; dkt++) {                     \
      _Pragma("unroll") for (int kvc = 0; kvc < 2; kvc++) {                   \
        const bf16x8 vv =                                                     \
            *(const bf16x8*)(Vc + dkt * 2048 + kvc * 1024 + laneK);           \
        _Pragma("unroll") for (int qt = 0; qt < 2; qt++)                      \
            oT[qt][dkt] = MFMA_BF16(vv, pb[qt][kvc].v8, oT[qt][dkt], 0, 0, 0);\
      }                                                                       \
    }                                                                         \
    __builtin_amdgcn_s_setprio(0);                                            \
  }

  STAGE(0, 0);

  const int NMC = L / 128;  // 32 macro-iters
  for (int mc = 0; mc < NMC - 1; mc++) {
    const int buf = mc & 1;
    asm volatile("s_waitcnt vmcnt(2)" ::: "memory");
    __builtin_amdgcn_s_barrier();
    __builtin_amdgcn_sched_barrier(0);
    STAGE(mc + 1, buf ^ 1);
    PHASE_A(buf);
    asm volatile("s_waitcnt vmcnt(4)" ::: "memory");
    __builtin_amdgcn_s_barrier();
    __builtin_amdgcn_sched_barrier(0);
    PHASE_B(buf);
  }
  {  // peeled last iteration: drain to 0 before the V reads
    const int buf = (NMC - 1) & 1;
    asm volatile("s_waitcnt vmcnt(2)" ::: "memory");
    __builtin_amdgcn_s_barrier();
    __builtin_amdgcn_sched_barrier(0);
    PHASE_A(buf);
    asm volatile("s_waitcnt vmcnt(0)" ::: "memory");
    __builtin_amdgcn_s_barrier();
    __builtin_amdgcn_sched_barrier(0);
    PHASE_B(buf);
  }
#undef STAGE
#undef PHASE_A
#undef PHASE_B

  // cross-group combine: g=1 waves hand partial (oT, ls) to matching g=0
  // wave via LDS scratch (qt0 in Kst, qt1 in Vst; stride 20 floats).
  __syncthreads();
  float* sc0 = (float*)&Kst[0][0];
  float* sc1 = (float*)&Vst[0][0];
  const int sidx = (ws * 64 + lane) * 20;
  if (g == 1) {
#pragma unroll
    for (int dkt = 0; dkt < 4; dkt++) {
      *(f32x4*)(sc0 + sidx + dkt * 4) = oT[0][dkt];
      *(f32x4*)(sc1 + sidx + dkt * 4) = oT[1][dkt];
    }
    sc0[sidx + 16] = ls[0];
    sc1[sidx + 16] = ls[1];
  }
  __syncthreads();
  if (g == 0) {
#pragma unroll
    for (int dkt = 0; dkt < 4; dkt++) {
      oT[0][dkt] += *(const f32x4*)(sc0 + sidx + dkt * 4);
      oT[1][dkt] += *(const f32x4*)(sc1 + sidx + dkt * 4);
    }
    ls[0] += sc0[sidx + 16];
    ls[1] += sc1[sidx + 16];

#pragma unroll
    for (int qt = 0; qt < 2; qt++) {
      float l = ls[qt];
      l += __shfl_xor(l, 16);
      l += __shfl_xor(l, 32);
      const float inv = 1.0f / l;
      const size_t row = (size_t)(tq0 + qt) * 16 + l16;
#pragma unroll
      for (int dkt = 0; dkt < 4; dkt++) {
        bf16x4 ov;
#pragma unroll
        for (int r = 0; r < 4; r++) ov[r] = (bf16_t)(oT[qt][dkt][r] * inv);
        *(bf16x4*)(O + row * 1024 + h * 64 + dkt * 16 + quad * 4) = ov;
      }
    }
  }
}

// ---------------------------------------------------------------------------
extern "C" void kernel_launch(void* const* d_in, const int* in_sizes, int n_in,
                              void* d_out, int out_size, void* d_ws,
                              size_t ws_size, hipStream_t stream) {
  const float* q  = (const float*)d_in[0];
  const float* k  = (const float*)d_in[1];
  const float* v  = (const float*)d_in[2];
  const float* wq = (const float*)d_in[3];
  const float* bq = (const float*)d_in[4];
  const float* wk = (const float*)d_in[5];
  const float* bk = (const float*)d_in[6];
  const float* wv = (const float*)d_in[7];
  const float* bv = (const float*)d_in[8];
  const float* wo = (const float*)d_in[9];
  const float* bo = (const float*)d_in[10];
  float* out = (float*)d_out;

  const int L = 4096, D = 1024;
  const int nLD = L * D;  // 4M
  const int nDD = D * D;  // 1M
  bf16_t* p = (bf16_t*)d_ws;
  bf16_t* qb  = p; p += nLD;
  bf16_t* kb  = p; p += nLD;
  bf16_t* vb  = p; p += nLD;
  bf16_t* wqb = p; p += nDD;
  bf16_t* wkb = p; p += nDD;
  bf16_t* wvb = p; p += nDD;
  bf16_t* wob = p; p += nDD;
  bf16_t* Op  = p; p += nLD;
  bf16_t* Qt  = p; p += nLD;
  bf16_t* Kt  = p; p += nLD;
  bf16_t* Vt  = p; p += nLD;

  dim3 blk(256);
  cast_f32_bf16<<<dim3(nLD / (256 * 8), 1, 7), blk, 0, stream>>>(
      q, qb, nLD, k, kb, nLD, v, vb, nLD, wq, wqb, nDD, wk, wkb, nDD,
      wv, wvb, nDD, wo, wob, nDD);
  gemm_qkv<<<dim3(L / 128, D / 128, 3), blk, 0, stream>>>(
      qb, wqb, bq, Qt, kb, wkb, bk, Kt, vb, wvb, bv, Vt, L, D, D);
  flash_attn<<<dim3((L / 128) * 16), dim3(512), 0, stream>>>(Qt, Kt, Vt, Op, L);
  gemm_out<<<dim3(L / 64, D / 128), blk, 0, stream>>>(Op, wob, bo, out, L, D,
                                                      D);
}